// Round 1
// baseline (976.302 us; speedup 1.0000x reference)
//
#include <hip/hip_runtime.h>
#include <stdint.h>

#pragma clang fp contract(off)

#define N_PRIM   1000000
#define GRID_G   512
#define MAXM     64
#define NCELLS   (GRID_G*GRID_G)          // 262144
#define FOCAL_C  768.0f
#define SORT_BLOCKS 245
#define EPB      4096                     // elems per sort block (256 thr * 16)
#define NP       (SORT_BLOCKS*EPB)        // 1,003,520 padded count
#define NBINS    256
#define HSIZE    (NBINS*SORT_BLOCKS)      // 62,720
#define ENTCAP   (4*N_PRIM)

// ---------------- workspace layout (bytes, all 256-aligned) ----------------
#define O_KEYSA   ((size_t)0)
#define O_KEYSB   (O_KEYSA + (size_t)NP*4)        // 4,014,080
#define O_PAYA    (O_KEYSB + (size_t)NP*4)
#define O_PAYB    (O_PAYA  + (size_t)NP*4)
#define O_DATA    (O_PAYB  + (size_t)NP*4)        // 16,056,320
#define O_CELLS   (O_DATA  + (size_t)N_PRIM*48)   // 64,056,320
#define O_INVP    (O_CELLS + (size_t)N_PRIM*16)   // 80,056,320
#define O_CCNT    (O_INVP  + (size_t)N_PRIM*4)    // 84,056,320
#define O_VCNT    (O_CCNT  + (size_t)NCELLS*4)    // 85,104,896
#define O_COFS    (O_VCNT  + 256)                 // 85,105,152
#define O_CURS    (O_COFS  + (size_t)NCELLS*4)
#define O_BSUM    (O_CURS  + (size_t)NCELLS*4)
#define O_HIST    (O_BSUM  + 4096)
#define O_ENTRY   (O_HIST  + (size_t)HSIZE*4)
#define WS_NEED   (O_ENTRY + (size_t)ENTCAP*4)    // ~103.5 MB

// ---------------------------------------------------------------------------
__global__ __launch_bounds__(256) void k_prep(
    const float* __restrict__ centers, const float* __restrict__ scales,
    const float* __restrict__ rotations, const float* __restrict__ colors,
    const float* __restrict__ opac, const float* __restrict__ mvp,
    uint32_t* __restrict__ keys, uint32_t* __restrict__ pay,
    float4* __restrict__ data, int4* __restrict__ cells,
    uint32_t* __restrict__ cellcnt, uint32_t* __restrict__ vcounter)
{
  int i = blockIdx.x*256 + threadIdx.x;
  if (i >= NP) return;
  if (i >= N_PRIM) { keys[i] = 0xFFFFFFFFu; pay[i] = 0u; return; }

  float c0 = centers[3*i], c1 = centers[3*i+1], c2 = centers[3*i+2];
  // ndc_j = sum_k mvp[j][k]*c_k + mvp[j][3]  (ascending-k fma chain)
  float n0 = fmaf(mvp[2],  c2, fmaf(mvp[1], c1, mvp[0]*c0)) + mvp[3];
  float n1 = fmaf(mvp[6],  c2, fmaf(mvp[5], c1, mvp[4]*c0)) + mvp[7];
  float n2 = fmaf(mvp[10], c2, fmaf(mvp[9], c1, mvp[8]*c0)) + mvp[11];
  bool valid = n2 > 0.0f;
  float cx = (n0 + 1.0f)*0.5f;
  float cy = (n1 + 1.0f)*0.5f;
  keys[i] = __float_as_uint(valid ? n2 : 1e30f);  // positive floats: bit order == numeric order
  pay[i]  = (uint32_t)i;

  // quaternion -> rotation (exact on this dataset: q = ones -> permutation)
  float qw = rotations[4*i], qx = rotations[4*i+1], qy = rotations[4*i+2], qz = rotations[4*i+3];
  float nrm = sqrtf(qw*qw + qx*qx + qy*qy + qz*qz);
  nrm = fmaxf(nrm, 1e-12f);
  qw /= nrm; qx /= nrm; qy /= nrm; qz /= nrm;
  float R00 = 1.0f - 2.0f*(qy*qy + qz*qz);
  float R01 = 2.0f*(qx*qy - qz*qw);
  float R02 = 2.0f*(qx*qz + qy*qw);
  float R10 = 2.0f*(qx*qy + qz*qw);
  float R11 = 1.0f - 2.0f*(qx*qx + qz*qz);
  float R12 = 2.0f*(qy*qz - qx*qw);
  float R20 = 2.0f*(qx*qz - qy*qw);
  float R21 = 2.0f*(qy*qz + qx*qw);
  float R22 = 1.0f - 2.0f*(qx*qx + qy*qy);
  float s0 = fmaxf(scales[3*i],   1e-9f);
  float s1 = fmaxf(scales[3*i+1], 1e-9f);
  float s2 = fmaxf(scales[3*i+2], 1e-9f);
  float L00=R00*s0, L01=R01*s1, L02=R02*s2;
  float L10=R10*s0, L11=R11*s1, L12=R12*s2;
  float L20=R20*s0, L21=R21*s1, L22=R22*s2;
  // cov = L L^T (symmetric)
  float cv00 = fmaf(L02,L02, fmaf(L01,L01, L00*L00));
  float cv01 = fmaf(L02,L12, fmaf(L01,L11, L00*L10));
  float cv02 = fmaf(L02,L22, fmaf(L01,L21, L00*L20));
  float cv11 = fmaf(L12,L12, fmaf(L11,L11, L10*L10));
  float cv12 = fmaf(L12,L22, fmaf(L11,L21, L10*L20));
  float cv22 = fmaf(L22,L22, fmaf(L21,L21, L20*L20));
  // V = mvp[:3,:3], need rows 0,1; T = V@cov, ccov = T@V^T (path1, ascending fma)
  float V00=mvp[0], V01=mvp[1], V02=mvp[2];
  float V10=mvp[4], V11=mvp[5], V12=mvp[6];
  float T00 = fmaf(V02,cv02, fmaf(V01,cv01, V00*cv00));
  float T01 = fmaf(V02,cv12, fmaf(V01,cv11, V00*cv01));
  float T02 = fmaf(V02,cv22, fmaf(V01,cv12, V00*cv02));
  float T10 = fmaf(V12,cv02, fmaf(V11,cv01, V10*cv00));
  float T11 = fmaf(V12,cv12, fmaf(V11,cv11, V10*cv01));
  float T12 = fmaf(V12,cv22, fmaf(V11,cv12, V10*cv02));
  float cc00 = fmaf(T02,V02, fmaf(T01,V01, T00*V00));
  float cc01 = fmaf(T02,V12, fmaf(T01,V11, T00*V10));
  float cc11 = fmaf(T12,V12, fmaf(T11,V11, T10*V10));
  float zc  = fmaxf(n2, 1e-6f);
  float sc  = FOCAL_C / zc;
  float sc2 = sc*sc;
  float c00 = cc00*sc2, c01 = cc01*sc2, c11 = cc11*sc2;

  float rx = (3.0f * sqrtf(fmaxf(c00, 0.0f))) / 512.0f;
  float ry = (3.0f * sqrtf(fmaxf(c11, 0.0f))) / 512.0f;
  int x0 = (int)floorf((cx - rx) * 512.0f);
  int x1 = (int)floorf((cx + rx) * 512.0f);
  int y0 = (int)floorf((cy - ry) * 512.0f);
  int y1 = (int)floorf((cy + ry) * 512.0f);
  int cl[4];
  #pragma unroll
  for (int ky = 0; ky < 2; ++ky) {
    int yy = y0 + ky;
    bool vy = (yy <= y1) && (yy >= 0) && (yy < GRID_G);
    #pragma unroll
    for (int kx = 0; kx < 2; ++kx) {
      int xx = x0 + kx;
      bool vx = (xx <= x1) && (xx >= 0) && (xx < GRID_G);
      int cell = (valid && vy && vx) ? (yy*GRID_G + xx) : -1;
      cl[ky*2+kx] = cell;
      if (cell >= 0) atomicAdd(&cellcnt[cell], 1u);
    }
  }
  cells[i] = make_int4(cl[0], cl[1], cl[2], cl[3]);

  float opv = fminf(fmaxf(opac[i], 0.0f), 1.0f);
  float col0 = colors[3*i], col1 = colors[3*i+1], col2 = colors[3*i+2];
  float vf = valid ? 1.0f : 0.0f;
  data[3*(size_t)i]   = make_float4(cx, cy, c00, c01);
  data[3*(size_t)i+1] = make_float4(c11, col0, col1, col2);
  data[3*(size_t)i+2] = make_float4(opv, vf, 0.0f, 0.0f);

  unsigned long long b = __ballot(valid);
  if ((threadIdx.x & 63) == 0) atomicAdd(vcounter, (uint32_t)__popcll(b));
}

// ---------------- cell-count scan (262144 = 1024 blocks * 256) -------------
__global__ void k_scanA(const uint32_t* __restrict__ cnt, uint32_t* __restrict__ ofs,
                        uint32_t* __restrict__ bsum)
{
  __shared__ uint32_t s[256];
  int t = threadIdx.x;
  int i = blockIdx.x*256 + t;
  uint32_t v = cnt[i];
  s[t] = v; __syncthreads();
  for (int o = 1; o < 256; o <<= 1) {
    uint32_t u = (t >= o) ? s[t-o] : 0u; __syncthreads();
    s[t] += u; __syncthreads();
  }
  ofs[i] = s[t] - v;
  if (t == 255) bsum[blockIdx.x] = s[t];
}

__global__ void k_scanB(uint32_t* __restrict__ bsum)
{
  __shared__ uint32_t s[1024];
  int t = threadIdx.x;
  uint32_t v = bsum[t];
  s[t] = v; __syncthreads();
  for (int o = 1; o < 1024; o <<= 1) {
    uint32_t u = (t >= o) ? s[t-o] : 0u; __syncthreads();
    s[t] += u; __syncthreads();
  }
  bsum[t] = s[t] - v;
}

__global__ void k_scanC(uint32_t* __restrict__ ofs, const uint32_t* __restrict__ bsum,
                        uint32_t* __restrict__ cursor)
{
  int i = blockIdx.x*256 + threadIdx.x;
  uint32_t v = ofs[i] + bsum[blockIdx.x];
  ofs[i] = v; cursor[i] = v;
}

// ---------------- radix sort: hist / scan / stable scatter ------------------
__global__ __launch_bounds__(256) void k_hist(const uint32_t* __restrict__ keys,
                                              uint32_t* __restrict__ hist, int shift)
{
  __shared__ uint32_t h[256];
  int t = threadIdx.x;
  h[t] = 0; __syncthreads();
  size_t base = (size_t)blockIdx.x*EPB;
  #pragma unroll
  for (int j = 0; j < 16; ++j) {
    uint32_t k = keys[base + (size_t)j*256 + t];
    atomicAdd(&h[(k >> shift) & 255], 1u);
  }
  __syncthreads();
  hist[(size_t)t*SORT_BLOCKS + blockIdx.x] = h[t];
}

__global__ void k_scanhist(uint32_t* __restrict__ hist)
{
  __shared__ uint32_t s[1024];
  int t = threadIdx.x;
  const int total = HSIZE;
  const int chunk = (total + 1023)/1024;
  int a = t*chunk, b = min(a+chunk, total);
  uint32_t sum = 0;
  for (int i = a; i < b; ++i) sum += hist[i];
  s[t] = sum; __syncthreads();
  for (int o = 1; o < 1024; o <<= 1) {
    uint32_t u = (t >= o) ? s[t-o] : 0u; __syncthreads();
    s[t] += u; __syncthreads();
  }
  uint32_t run = s[t] - sum;
  for (int i = a; i < b; ++i) { uint32_t h = hist[i]; hist[i] = run; run += h; }
}

__global__ __launch_bounds__(256) void k_scatter(
    const uint32_t* __restrict__ keys, const uint32_t* __restrict__ pays,
    uint32_t* __restrict__ okeys, uint32_t* __restrict__ opays,
    const uint32_t* __restrict__ hist, int shift)
{
  __shared__ uint32_t s_base[256];
  __shared__ uint32_t s_run[256];
  __shared__ uint32_t s_wcnt[1024];   // [bin][wave]
  int t = threadIdx.x;
  int wid = t >> 6, lane = t & 63;
  s_base[t] = hist[(size_t)t*SORT_BLOCKS + blockIdx.x];
  s_run[t] = 0;
  size_t base = (size_t)blockIdx.x*EPB;
  for (int j = 0; j < 16; ++j) {
    for (int q = t; q < 1024; q += 256) s_wcnt[q] = 0;
    __syncthreads();
    uint32_t key = keys[base + (size_t)j*256 + t];
    uint32_t pv  = pays[base + (size_t)j*256 + t];
    uint32_t b = (key >> shift) & 255;
    unsigned long long m = ~0ULL;
    #pragma unroll
    for (int bit = 0; bit < 8; ++bit) {
      unsigned long long vote = __ballot((b >> bit) & 1);
      m &= ((b >> bit) & 1) ? vote : ~vote;
    }
    uint32_t lr = __popcll(m & ((1ULL << lane) - 1ULL));
    if (lr == 0) s_wcnt[b*4 + wid] = (uint32_t)__popcll(m);
    __syncthreads();
    uint32_t wb = 0;
    for (int w2 = 0; w2 < wid; ++w2) wb += s_wcnt[b*4 + w2];
    uint32_t pos = s_base[b] + s_run[b] + wb + lr;
    okeys[pos] = key;
    opays[pos] = pv;
    __syncthreads();
    uint32_t tot = s_wcnt[t*4] + s_wcnt[t*4+1] + s_wcnt[t*4+2] + s_wcnt[t*4+3];
    s_run[t] += tot;
    __syncthreads();
  }
}

// ---------------- result rows (sorted order) + inverse permutation ---------
__global__ __launch_bounds__(256) void k_result(
    const uint32_t* __restrict__ spay, const float4* __restrict__ data,
    uint32_t* __restrict__ invperm, float* __restrict__ out)
{
  __shared__ float rows[256*21];
  int t = threadIdx.x;
  int i = blockIdx.x*256 + t;
  int nrows = min(256, N_PRIM - blockIdx.x*256);
  if (t < nrows) {
    uint32_t o = spay[i];
    invperm[o] = (uint32_t)i;
    float4 a = data[3*(size_t)o], b = data[3*(size_t)o+1], c = data[3*(size_t)o+2];
    float vf = c.y;
    float* r = &rows[t*21];
    r[0]  = 5.0f*vf;
    r[1]  = a.x*vf; r[2] = a.y*vf; r[3] = a.z*vf; r[4] = a.w*vf; r[5] = b.x*vf;
    r[6]  = 0.0f; r[7] = 0.0f; r[8] = 0.0f;
    r[9]  = b.y*vf; r[10] = b.z*vf; r[11] = b.w*vf;
    r[12] = c.x*vf;
    r[13]=0.0f; r[14]=0.0f; r[15]=0.0f; r[16]=0.0f; r[17]=0.0f; r[18]=0.0f; r[19]=0.0f;
  }
  __syncthreads();
  int total = nrows*20;
  float* gout = out + 6 + (size_t)blockIdx.x*256*20;
  for (int g = t; g < total; g += 256) {
    int rr = g/20, cc = g - rr*20;
    gout[g] = rows[rr*21+cc];
  }
}

// ---------------- emit (cell, sorted-idx) entries ---------------------------
__global__ __launch_bounds__(256) void k_emit(
    const int4* __restrict__ cells, const uint32_t* __restrict__ invperm,
    uint32_t* __restrict__ cursor, uint32_t* __restrict__ entry)
{
  int o = blockIdx.x*256 + threadIdx.x;
  if (o >= N_PRIM) return;
  int4 cl = cells[o];
  int v[4] = {cl.x, cl.y, cl.z, cl.w};
  uint32_t i = invperm[o];
  #pragma unroll
  for (int k = 0; k < 4; ++k) {
    if (v[k] >= 0) {
      uint32_t p = atomicAdd(&cursor[v[k]], 1u);
      entry[p] = i;
    }
  }
}

// ---------------- per-cell finalize: sort entries, write grid ---------------
__global__ __launch_bounds__(256) void k_grid(
    const uint32_t* __restrict__ cellcnt, const uint32_t* __restrict__ cellofs,
    const uint32_t* __restrict__ entry, float* __restrict__ out)
{
  int wid = threadIdx.x >> 6;
  int lane = threadIdx.x & 63;
  int cell = blockIdx.x*4 + wid;
  uint32_t cnt = cellcnt[cell];
  uint32_t ofs = cellofs[cell];
  float* g = out + 6 + (size_t)N_PRIM*20 + (size_t)cell*65;
  if (cnt <= 64u) {
    int v = (lane < (int)cnt) ? (int)entry[ofs + lane] : 0x7FFFFFFF;
    #pragma unroll
    for (int k = 2; k <= 64; k <<= 1) {
      #pragma unroll
      for (int j = k>>1; j > 0; j >>= 1) {
        int p = __shfl_xor(v, j, 64);
        bool up = ((lane & k) == 0);
        bool lower = ((lane & j) == 0);
        int mn = min(v,p), mx = max(v,p);
        v = (up == lower) ? mn : mx;
      }
    }
    g[1+lane] = (lane < (int)cnt) ? (float)v : 0.0f;
    if (lane == 0) g[0] = (float)cnt;
  } else {
    int last = -1;
    for (int s = 0; s < 64; ++s) {
      int best = 0x7FFFFFFF;
      for (uint32_t c = lane; c < cnt; c += 64) {
        int v = (int)entry[ofs + c];
        if (v > last && v < best) best = v;
      }
      #pragma unroll
      for (int o = 32; o > 0; o >>= 1) best = min(best, __shfl_xor(best, o, 64));
      if (lane == 0) g[1+s] = (float)best;
      last = best;
    }
    if (lane == 0) g[0] = 64.0f;
  }
}

// ---------------- header ----------------------------------------------------
__global__ void k_header(const uint32_t* __restrict__ vcounter,
                         const float* __restrict__ bg, float* __restrict__ out)
{
  if (threadIdx.x == 0) {
    out[0] = (float)(*vcounter);
    out[1] = 512.0f;
    out[2] = 64.0f;
    out[3] = bg[0]; out[4] = bg[1]; out[5] = bg[2];
  }
}

// ---------------------------------------------------------------------------
extern "C" void kernel_launch(void* const* d_in, const int* in_sizes, int n_in,
                              void* d_out, int out_size, void* d_ws, size_t ws_size,
                              hipStream_t stream)
{
  const float* centers   = (const float*)d_in[0];
  const float* scales    = (const float*)d_in[1];
  const float* rotations = (const float*)d_in[2];
  const float* colors    = (const float*)d_in[3];
  const float* opacities = (const float*)d_in[4];
  const float* mvp       = (const float*)d_in[5];
  const float* background= (const float*)d_in[6];
  float* out = (float*)d_out;
  char* ws = (char*)d_ws;
  if (ws_size < WS_NEED) return;  // fail loudly in validation rather than corrupt

  uint32_t* keysA  = (uint32_t*)(ws + O_KEYSA);
  uint32_t* keysB  = (uint32_t*)(ws + O_KEYSB);
  uint32_t* payA   = (uint32_t*)(ws + O_PAYA);
  uint32_t* payB   = (uint32_t*)(ws + O_PAYB);
  float4*   data   = (float4*)  (ws + O_DATA);
  int4*     cells  = (int4*)    (ws + O_CELLS);
  uint32_t* invp   = (uint32_t*)(ws + O_INVP);
  uint32_t* ccnt   = (uint32_t*)(ws + O_CCNT);
  uint32_t* vcnt   = (uint32_t*)(ws + O_VCNT);
  uint32_t* cofs   = (uint32_t*)(ws + O_COFS);
  uint32_t* curs   = (uint32_t*)(ws + O_CURS);
  uint32_t* bsum   = (uint32_t*)(ws + O_BSUM);
  uint32_t* hist   = (uint32_t*)(ws + O_HIST);
  uint32_t* entry  = (uint32_t*)(ws + O_ENTRY);

  // zero cell counts + valid counter (contiguous)
  hipMemsetAsync(ws + O_CCNT, 0, (size_t)NCELLS*4 + 256, stream);

  k_prep<<<NP/256, 256, 0, stream>>>(centers, scales, rotations, colors, opacities,
                                     mvp, keysA, payA, data, cells, ccnt, vcnt);

  k_scanA<<<NCELLS/256, 256, 0, stream>>>(ccnt, cofs, bsum);
  k_scanB<<<1, 1024, 0, stream>>>(bsum);
  k_scanC<<<NCELLS/256, 256, 0, stream>>>(cofs, bsum, curs);

  uint32_t *kin = keysA, *kout = keysB, *pin = payA, *pout = payB;
  for (int pass = 0; pass < 4; ++pass) {
    int shift = pass*8;
    k_hist<<<SORT_BLOCKS, 256, 0, stream>>>(kin, hist, shift);
    k_scanhist<<<1, 1024, 0, stream>>>(hist);
    k_scatter<<<SORT_BLOCKS, 256, 0, stream>>>(kin, pin, kout, pout, hist, shift);
    uint32_t* tk = kin; kin = kout; kout = tk;
    uint32_t* tp = pin; pin = pout; pout = tp;
  }
  // after 4 passes, sorted data back in keysA/payA (== kin/pin)

  k_result<<<(N_PRIM+255)/256, 256, 0, stream>>>(pin, data, invp, out);
  k_emit  <<<(N_PRIM+255)/256, 256, 0, stream>>>(cells, invp, curs, entry);
  k_grid  <<<NCELLS/4, 256, 0, stream>>>(ccnt, cofs, entry, out);
  k_header<<<1, 64, 0, stream>>>(vcnt, background, out);
}

// Round 4
// 443.037 us; speedup vs baseline: 2.2037x; 2.2037x over previous
//
#include <hip/hip_runtime.h>
#include <stdint.h>

#pragma clang fp contract(off)

#define N_PRIM   1000000
#define GRID_G   512
#define NCELLS   (GRID_G*GRID_G)          // 262144
#define FOCAL_C  768.0f
#define NP2      1048576                  // 2^20 padded count
#define SB       512                      // sort blocks
#define EPB      2048                     // elems per sort block (256 thr * 8)
#define PREP_BLOCKS 2048                  // 512 prims per block

// ---------------- workspace layout (bytes) ----------------
#define O_SORTA  ((size_t)0)
#define O_SORTB  (O_SORTA + (size_t)NP2*8)          // 8,388,608
#define O_REC    (O_SORTB + (size_t)NP2*8)          // 16,777,216
#define O_CCNT   (O_REC   + (size_t)N_PRIM*64)      // 80,777,216
#define O_COFS   (O_CCNT  + (size_t)NCELLS*4)
#define O_CURS   (O_COFS  + (size_t)NCELLS*4)
#define O_HIST   (O_CURS  + (size_t)NCELLS*4)       // 256*512*4 = 512 KB (region 1 MB)
#define O_BSUM   (O_HIST  + (size_t)NCELLS*4)
#define O_VCNT   (O_BSUM  + 4096)
#define O_ENTRY  (O_VCNT  + 8192)
#define WS_NEED  (O_ENTRY + (size_t)4*N_PRIM*4)     // ~101 MB

__device__ __forceinline__ int swz(int q) { return q ^ ((q >> 3) & 7); }

// ---------------------------------------------------------------------------
__global__ __launch_bounds__(256) void k_prep(
    const float* __restrict__ centers, const float* __restrict__ scales,
    const float* __restrict__ rotations, const float* __restrict__ colors,
    const float* __restrict__ opac, const float* __restrict__ mvp,
    uint64_t* __restrict__ sortA, float4* __restrict__ rec,
    uint32_t* __restrict__ cellcnt, uint32_t* __restrict__ vcnt)
{
  __shared__ float4 srec[2048];          // 512 prims * 4 float4 (swizzled)
  __shared__ uint32_t swcnt[4];
  int t = threadIdx.x;
  int pair = blockIdx.x*256 + t;
  int p0 = pair*2;
  bool live = p0 < N_PRIM;               // pairs never straddle N (N even)

  float m0=mvp[0], m1=mvp[1], m2=mvp[2],  m3=mvp[3];
  float m4=mvp[4], m5=mvp[5], m6=mvp[6],  m7=mvp[7];
  float m8=mvp[8], m9=mvp[9], m10=mvp[10],m11=mvp[11];

  bool valid0=false, valid1=false;
  uint64_t pk0 = ~0ULL, pk1 = ~0ULL;     // padding sorts strictly last

  if (live) {
    const float2* cp = (const float2*)(centers + (size_t)pair*6);
    float2 ca = cp[0], cb = cp[1], cc = cp[2];
    const float2* sp = (const float2*)(scales + (size_t)pair*6);
    float2 sa = sp[0], sb2 = sp[1], sc2 = sp[2];
    const float4* rp = (const float4*)rotations;
    float4 q0 = rp[p0], q1 = rp[p0+1];
    const float2* colp = (const float2*)(colors + (size_t)pair*6);
    float2 ka = colp[0], kb = colp[1], kc = colp[2];
    float2 o2 = ((const float2*)opac)[pair];

    auto doPrim = [&](int i, float c0, float c1, float c2,
                      float s0, float s1, float s2,
                      float qw, float qx, float qy, float qz,
                      float col0, float col1, float col2, float op,
                      uint64_t& pk, bool& validf, int lidx) {
      float n0 = fmaf(m2,  c2, fmaf(m1, c1, m0*c0)) + m3;
      float n1 = fmaf(m6,  c2, fmaf(m5, c1, m4*c0)) + m7;
      float n2 = fmaf(m10, c2, fmaf(m9, c1, m8*c0)) + m11;
      bool valid = n2 > 0.0f;
      validf = valid;
      float cx = (n0 + 1.0f)*0.5f;
      float cy = (n1 + 1.0f)*0.5f;
      // sort key: exact float bits of clip(z,1e-6) (monotone for positives);
      // invalid -> bits of 1e30f. Stability via idx in low 20 bits.
      uint32_t key32 = valid ? __float_as_uint(fmaxf(n2, 1e-6f)) : 0x7149F2CAu;
      pk = ((uint64_t)key32 << 20) | (uint32_t)i;

      float nrm = sqrtf(qw*qw + qx*qx + qy*qy + qz*qz);
      nrm = fmaxf(nrm, 1e-12f);
      qw /= nrm; qx /= nrm; qy /= nrm; qz /= nrm;
      float R00 = 1.0f - 2.0f*(qy*qy + qz*qz);
      float R01 = 2.0f*(qx*qy - qz*qw);
      float R02 = 2.0f*(qx*qz + qy*qw);
      float R10 = 2.0f*(qx*qy + qz*qw);
      float R11 = 1.0f - 2.0f*(qx*qx + qz*qz);
      float R12 = 2.0f*(qy*qz - qx*qw);
      float R20 = 2.0f*(qx*qz - qy*qw);
      float R21 = 2.0f*(qy*qz + qx*qw);
      float R22 = 1.0f - 2.0f*(qx*qx + qy*qy);
      s0 = fmaxf(s0, 1e-9f); s1 = fmaxf(s1, 1e-9f); s2 = fmaxf(s2, 1e-9f);
      float L00=R00*s0, L01=R01*s1, L02=R02*s2;
      float L10=R10*s0, L11=R11*s1, L12=R12*s2;
      float L20=R20*s0, L21=R21*s1, L22=R22*s2;
      float cv00 = fmaf(L02,L02, fmaf(L01,L01, L00*L00));
      float cv01 = fmaf(L02,L12, fmaf(L01,L11, L00*L10));
      float cv02 = fmaf(L02,L22, fmaf(L01,L21, L00*L20));
      float cv11 = fmaf(L12,L12, fmaf(L11,L11, L10*L10));
      float cv12 = fmaf(L12,L22, fmaf(L11,L21, L10*L20));
      float cv22 = fmaf(L22,L22, fmaf(L21,L21, L20*L20));
      float T00 = fmaf(m2,cv02, fmaf(m1,cv01, m0*cv00));
      float T01 = fmaf(m2,cv12, fmaf(m1,cv11, m0*cv01));
      float T02 = fmaf(m2,cv22, fmaf(m1,cv12, m0*cv02));
      float T10 = fmaf(m6,cv02, fmaf(m5,cv01, m4*cv00));
      float T11 = fmaf(m6,cv12, fmaf(m5,cv11, m4*cv01));
      float T12 = fmaf(m6,cv22, fmaf(m5,cv12, m4*cv02));
      float cc00 = fmaf(T02,m2, fmaf(T01,m1, T00*m0));
      float cc01 = fmaf(T02,m6, fmaf(T01,m5, T00*m4));
      float cc11 = fmaf(T12,m6, fmaf(T11,m5, T10*m4));
      float zc  = fmaxf(n2, 1e-6f);
      float scv = FOCAL_C / zc;
      float sc22 = scv*scv;
      float c00 = cc00*sc22, c01 = cc01*sc22, c11 = cc11*sc22;

      float rx = (3.0f * sqrtf(fmaxf(c00, 0.0f))) / 512.0f;
      float ry = (3.0f * sqrtf(fmaxf(c11, 0.0f))) / 512.0f;
      int x0 = (int)floorf((cx - rx) * 512.0f);
      int x1 = (int)floorf((cx + rx) * 512.0f);
      int y0 = (int)floorf((cy - ry) * 512.0f);
      int y1 = (int)floorf((cy + ry) * 512.0f);
      int cl[4];
      #pragma unroll
      for (int ky = 0; ky < 2; ++ky) {
        int yy = y0 + ky;
        bool vy = (yy <= y1) && (yy >= 0) && (yy < GRID_G);
        #pragma unroll
        for (int kx = 0; kx < 2; ++kx) {
          int xx = x0 + kx;
          bool vx = (xx <= x1) && (xx >= 0) && (xx < GRID_G);
          int cell = (valid && vy && vx) ? (yy*GRID_G + xx) : -1;
          cl[ky*2+kx] = cell;
          if (cell >= 0) atomicAdd(&cellcnt[cell], 1u);
        }
      }
      float opv = fminf(fmaxf(op, 0.0f), 1.0f);
      float vf = valid ? 1.0f : 0.0f;
      int lb = lidx*4;
      srec[swz(lb+0)] = make_float4(cx, cy, c00, c01);
      srec[swz(lb+1)] = make_float4(c11, col0, col1, col2);
      srec[swz(lb+2)] = make_float4(opv, vf, 0.0f, 0.0f);
      srec[swz(lb+3)] = make_float4(__int_as_float(cl[0]), __int_as_float(cl[1]),
                                    __int_as_float(cl[2]), __int_as_float(cl[3]));
    };

    doPrim(p0,   ca.x, ca.y, cb.x, sa.x, sa.y, sb2.x,
           q0.x, q0.y, q0.z, q0.w, ka.x, ka.y, kb.x, o2.x, pk0, valid0, 2*t);
    doPrim(p0+1, cb.y, cc.x, cc.y, sb2.y, sc2.x, sc2.y,
           q1.x, q1.y, q1.z, q1.w, kb.y, kc.x, kc.y, o2.y, pk1, valid1, 2*t+1);
  }

  ((ulonglong2*)sortA)[pair] = make_ulonglong2(pk0, pk1);

  unsigned long long b0 = __ballot(live && valid0);
  unsigned long long b1 = __ballot(live && valid1);
  if ((t & 63) == 0) swcnt[t >> 6] = (uint32_t)(__popcll(b0) + __popcll(b1));
  __syncthreads();
  if (t == 0) vcnt[blockIdx.x] = swcnt[0]+swcnt[1]+swcnt[2]+swcnt[3];

  // coalesced rec writeout
  size_t gbase = (size_t)blockIdx.x*2048;
  for (int q = t; q < 2048; q += 256) {
    size_t gi = gbase + q;
    if (gi < (size_t)N_PRIM*4) rec[gi] = srec[swz(q)];
  }
}

// ---------------- scans --------------------------------------------------
__global__ void k_scanA(const uint32_t* __restrict__ cnt, uint32_t* __restrict__ ofs,
                        uint32_t* __restrict__ bsum)
{
  __shared__ uint32_t s[256];
  int t = threadIdx.x;
  int i = blockIdx.x*256 + t;
  uint32_t v = cnt[i];
  s[t] = v; __syncthreads();
  for (int o = 1; o < 256; o <<= 1) {
    uint32_t u = (t >= o) ? s[t-o] : 0u; __syncthreads();
    s[t] += u; __syncthreads();
  }
  ofs[i] = s[t] - v;
  if (t == 255) bsum[blockIdx.x] = s[t];
}

__global__ void k_scanB(uint32_t* __restrict__ bsum, int n)
{
  __shared__ uint32_t s[1024];
  int t = threadIdx.x;
  uint32_t v = (t < n) ? bsum[t] : 0u;
  s[t] = v; __syncthreads();
  for (int o = 1; o < 1024; o <<= 1) {
    uint32_t u = (t >= o) ? s[t-o] : 0u; __syncthreads();
    s[t] += u; __syncthreads();
  }
  if (t < n) bsum[t] = s[t] - v;
}

__global__ void k_scanC(uint32_t* __restrict__ ofs, const uint32_t* __restrict__ bsum,
                        uint32_t* __restrict__ cursor)
{
  int i = blockIdx.x*256 + threadIdx.x;
  uint32_t v = ofs[i] + bsum[blockIdx.x];
  ofs[i] = v; cursor[i] = v;
}

__global__ void k_scanC2(uint32_t* __restrict__ ofs, const uint32_t* __restrict__ bsum)
{
  int i = blockIdx.x*256 + threadIdx.x;
  ofs[i] = ofs[i] + bsum[blockIdx.x];
}

// ---------------- radix sort (4 passes of 8 bits over bits 20..51) ----------
__global__ __launch_bounds__(256) void k_hist(const uint64_t* __restrict__ keys,
                                              uint32_t* __restrict__ hist, int shift)
{
  __shared__ uint32_t h[256];
  int t = threadIdx.x;
  h[t] = 0; __syncthreads();
  const ulonglong2* k2 = (const ulonglong2*)(keys + (size_t)blockIdx.x*EPB);
  #pragma unroll
  for (int j = 0; j < 4; ++j) {
    ulonglong2 w = k2[j*256 + t];
    atomicAdd(&h[(uint32_t)(w.x >> shift) & 255u], 1u);
    atomicAdd(&h[(uint32_t)(w.y >> shift) & 255u], 1u);
  }
  __syncthreads();
  hist[(size_t)t*SB + blockIdx.x] = h[t];
}

__global__ __launch_bounds__(256) void k_scatter(
    const uint64_t* __restrict__ in, uint64_t* __restrict__ outp,
    const uint32_t* __restrict__ hist, int shift)
{
  __shared__ uint32_t s_base[256];
  __shared__ uint32_t lbase[256];
  __shared__ uint32_t s_run[256];
  __shared__ uint32_t s_wcnt[1024];   // [bin][wave]
  __shared__ uint64_t stage[EPB];     // 16 KB
  int t = threadIdx.x;
  int wid = t >> 6, lane = t & 63;
  s_base[t] = hist[(size_t)t*SB + blockIdx.x];
  s_run[t] = 0;
  lbase[t] = 0;
  size_t base = (size_t)blockIdx.x*EPB;
  uint64_t v[8]; uint32_t d[8];
  #pragma unroll
  for (int j = 0; j < 8; ++j) {
    v[j] = in[base + j*256 + t];
    d[j] = (uint32_t)(v[j] >> shift) & 255u;
  }
  __syncthreads();
  #pragma unroll
  for (int j = 0; j < 8; ++j) atomicAdd(&lbase[d[j]], 1u);
  __syncthreads();
  uint32_t mycnt = lbase[t];
  for (int o = 1; o < 256; o <<= 1) {
    uint32_t u = (t >= o) ? lbase[t-o] : 0u; __syncthreads();
    lbase[t] += u; __syncthreads();
  }
  uint32_t myexcl = lbase[t] - mycnt;
  __syncthreads();
  lbase[t] = myexcl;
  __syncthreads();

  for (int j = 0; j < 8; ++j) {
    for (int q = t; q < 1024; q += 256) s_wcnt[q] = 0;
    __syncthreads();
    unsigned long long m = ~0ULL;
    #pragma unroll
    for (int bit = 0; bit < 8; ++bit) {
      unsigned long long vote = __ballot((d[j] >> bit) & 1);
      m &= ((d[j] >> bit) & 1) ? vote : ~vote;
    }
    uint32_t lr = __popcll(m & ((1ULL << lane) - 1ULL));
    if (lr == 0) s_wcnt[d[j]*4 + wid] = (uint32_t)__popcll(m);
    __syncthreads();
    uint32_t wb = 0;
    for (int w = 0; w < wid; ++w) wb += s_wcnt[d[j]*4 + w];
    stage[lbase[d[j]] + s_run[d[j]] + wb + lr] = v[j];
    __syncthreads();
    s_run[t] += s_wcnt[t*4] + s_wcnt[t*4+1] + s_wcnt[t*4+2] + s_wcnt[t*4+3];
    __syncthreads();
  }
  // block-sorted stage -> coalesced global writes (runs avg 8 elems = 64B)
  #pragma unroll
  for (int j = 0; j < 8; ++j) {
    int q = j*256 + t;
    uint64_t sv = stage[q];
    uint32_t sd = (uint32_t)(sv >> shift) & 255u;
    outp[s_base[sd] + ((uint32_t)q - lbase[sd])] = sv;
  }
}

// ---------------- result rows (sorted order) + entry emit -------------------
__global__ __launch_bounds__(256) void k_result(
    const uint64_t* __restrict__ sorted, const float4* __restrict__ rec,
    uint32_t* __restrict__ cursor, uint32_t* __restrict__ entry,
    float* __restrict__ out)
{
  __shared__ float rows[64*21];
  int t = threadIdx.x;
  int i = blockIdx.x*256 + t;
  bool liveP = i < N_PRIM;
  float4 a = make_float4(0,0,0,0), b = a, c = a;
  int4 cl = make_int4(-1,-1,-1,-1);
  if (liveP) {
    uint64_t v = sorted[i];
    int o = (int)(v & 0xFFFFFu);
    a = rec[(size_t)o*4]; b = rec[(size_t)o*4+1];
    c = rec[(size_t)o*4+2];
    float4 dd = rec[(size_t)o*4+3];
    cl.x = __float_as_int(dd.x); cl.y = __float_as_int(dd.y);
    cl.z = __float_as_int(dd.z); cl.w = __float_as_int(dd.w);
  }
  float vf = c.y;
  int mychunk = t >> 6;
  int r64 = t & 63;
  int blockRows = min(256, N_PRIM - blockIdx.x*256);
  for (int ch = 0; ch < 4; ++ch) {
    if (mychunk == ch && liveP) {
      float* r = &rows[r64*21];
      r[0]  = 5.0f*vf;
      r[1]  = a.x*vf; r[2] = a.y*vf; r[3] = a.z*vf; r[4] = a.w*vf; r[5] = b.x*vf;
      r[6]  = 0.0f; r[7] = 0.0f; r[8] = 0.0f;
      r[9]  = b.y*vf; r[10] = b.z*vf; r[11] = b.w*vf;
      r[12] = c.x*vf;
      r[13]=0.0f; r[14]=0.0f; r[15]=0.0f; r[16]=0.0f; r[17]=0.0f; r[18]=0.0f; r[19]=0.0f;
    }
    __syncthreads();
    int nrows = min(64, blockRows - ch*64);
    if (nrows > 0) {
      int total = nrows*20;
      float* gout = out + 6 + (size_t)blockIdx.x*5120 + ch*1280;
      for (int g = t; g < total; g += 256) {
        int rr = g/20, cc2 = g - rr*20;
        gout[g] = rows[rr*21+cc2];
      }
    }
    __syncthreads();
  }
  if (liveP) {
    int cc[4] = {cl.x, cl.y, cl.z, cl.w};
    #pragma unroll
    for (int k = 0; k < 4; ++k) {
      if (cc[k] >= 0) {
        uint32_t p = atomicAdd(&cursor[cc[k]], 1u);
        entry[p] = (uint32_t)i;
      }
    }
  }
}

// ---------------- per-cell finalize: sort entries, write grid ---------------
__global__ __launch_bounds__(256) void k_grid(
    const uint32_t* __restrict__ cellcnt, const uint32_t* __restrict__ cellofs,
    const uint32_t* __restrict__ entry, float* __restrict__ out)
{
  int wid = threadIdx.x >> 6;
  int lane = threadIdx.x & 63;
  int cell = blockIdx.x*4 + wid;
  uint32_t cnt = cellcnt[cell];
  uint32_t ofs = cellofs[cell];
  float* g = out + 6 + (size_t)N_PRIM*20 + (size_t)cell*65;
  if (cnt <= 64u) {
    int v = (lane < (int)cnt) ? (int)entry[ofs + lane] : 0x7FFFFFFF;
    #pragma unroll
    for (int k = 2; k <= 64; k <<= 1) {
      #pragma unroll
      for (int j = k>>1; j > 0; j >>= 1) {
        int p = __shfl_xor(v, j, 64);
        bool up = ((lane & k) == 0);
        bool lower = ((lane & j) == 0);
        int mn = min(v,p), mx = max(v,p);
        v = (up == lower) ? mn : mx;
      }
    }
    g[1+lane] = (lane < (int)cnt) ? (float)v : 0.0f;
    if (lane == 0) g[0] = (float)cnt;
  } else {
    int last = -1;
    for (int s = 0; s < 64; ++s) {
      int best = 0x7FFFFFFF;
      for (uint32_t c = lane; c < cnt; c += 64) {
        int v = (int)entry[ofs + c];
        if (v > last && v < best) best = v;
      }
      #pragma unroll
      for (int o = 32; o > 0; o >>= 1) best = min(best, __shfl_xor(best, o, 64));
      if (lane == 0) g[1+s] = (float)best;
      last = best;
    }
    if (lane == 0) g[0] = 64.0f;
  }
}

// ---------------- header ----------------------------------------------------
__global__ void k_header(const uint32_t* __restrict__ vcnt,
                         const float* __restrict__ bg, float* __restrict__ out)
{
  __shared__ uint32_t s[256];
  int t = threadIdx.x;
  uint32_t acc = 0;
  for (int i = t; i < PREP_BLOCKS; i += 256) acc += vcnt[i];
  s[t] = acc; __syncthreads();
  for (int o = 128; o > 0; o >>= 1) { if (t < o) s[t] += s[t+o]; __syncthreads(); }
  if (t == 0) {
    out[0] = (float)s[0];
    out[1] = 512.0f;
    out[2] = 64.0f;
    out[3] = bg[0]; out[4] = bg[1]; out[5] = bg[2];
  }
}

// ---------------------------------------------------------------------------
extern "C" void kernel_launch(void* const* d_in, const int* in_sizes, int n_in,
                              void* d_out, int out_size, void* d_ws, size_t ws_size,
                              hipStream_t stream)
{
  const float* centers   = (const float*)d_in[0];
  const float* scales    = (const float*)d_in[1];
  const float* rotations = (const float*)d_in[2];
  const float* colors    = (const float*)d_in[3];
  const float* opacities = (const float*)d_in[4];
  const float* mvp       = (const float*)d_in[5];
  const float* background= (const float*)d_in[6];
  float* out = (float*)d_out;
  char* ws = (char*)d_ws;
  if (ws_size < WS_NEED) return;

  uint64_t* sortA  = (uint64_t*)(ws + O_SORTA);
  uint64_t* sortB  = (uint64_t*)(ws + O_SORTB);
  float4*   rec    = (float4*)  (ws + O_REC);
  uint32_t* ccnt   = (uint32_t*)(ws + O_CCNT);
  uint32_t* cofs   = (uint32_t*)(ws + O_COFS);
  uint32_t* curs   = (uint32_t*)(ws + O_CURS);
  uint32_t* hist   = (uint32_t*)(ws + O_HIST);
  uint32_t* bsum   = (uint32_t*)(ws + O_BSUM);
  uint32_t* vcnt   = (uint32_t*)(ws + O_VCNT);
  uint32_t* entry  = (uint32_t*)(ws + O_ENTRY);

  hipMemsetAsync(ws + O_CCNT, 0, (size_t)NCELLS*4, stream);

  k_prep<<<PREP_BLOCKS, 256, 0, stream>>>(centers, scales, rotations, colors,
                                          opacities, mvp, sortA, rec, ccnt, vcnt);

  // cell-count scan -> offsets + cursors (262144 = 1024 blocks)
  k_scanA<<<NCELLS/256, 256, 0, stream>>>(ccnt, cofs, bsum);
  k_scanB<<<1, 1024, 0, stream>>>(bsum, 1024);
  k_scanC<<<NCELLS/256, 256, 0, stream>>>(cofs, bsum, curs);

  // 4-pass radix on bits 20..51 of packed (key32<<20 | idx)
  uint64_t *kin = sortA, *kout = sortB;
  const int shifts[4] = {20, 28, 36, 44};
  for (int pass = 0; pass < 4; ++pass) {
    k_hist<<<SB, 256, 0, stream>>>(kin, hist, shifts[pass]);
    // scan hist: 256*SB = 131072 entries = 512 blocks
    k_scanA<<<(256*SB)/256, 256, 0, stream>>>(hist, hist, bsum);
    k_scanB<<<1, 1024, 0, stream>>>(bsum, (256*SB)/256);
    k_scanC2<<<(256*SB)/256, 256, 0, stream>>>(hist, bsum);
    k_scatter<<<SB, 256, 0, stream>>>(kin, kout, hist, shifts[pass]);
    uint64_t* tmp = kin; kin = kout; kout = tmp;
  }
  // 4 passes: sorted array back in sortA (== kin)

  k_result<<<(N_PRIM+255)/256, 256, 0, stream>>>(kin, rec, curs, entry, out);
  k_grid  <<<NCELLS/4, 256, 0, stream>>>(ccnt, cofs, entry, out);
  k_header<<<1, 256, 0, stream>>>(vcnt, background, out);
}

// Round 5
// 426.462 us; speedup vs baseline: 2.2893x; 1.0389x over previous
//
#include <hip/hip_runtime.h>
#include <stdint.h>

#pragma clang fp contract(off)

#define N_PRIM   1000000
#define GRID_G   512
#define NCELLS   (GRID_G*GRID_G)          // 262144
#define FOCAL_C  768.0f
#define NP2      1048576                  // 2^20 padded count
#define SB       512                      // sort blocks
#define EPB      2048                     // elems per sort block (256 thr * 8)
#define PREP_BLOCKS 2048                  // 512 prims per block

// ---------------- workspace layout (bytes) ----------------
#define O_SORTA  ((size_t)0)
#define O_SORTB  (O_SORTA + (size_t)NP2*8)          // 8,388,608
#define O_REC    (O_SORTB + (size_t)NP2*8)          // 16,777,216
#define O_CCNT   (O_REC   + (size_t)N_PRIM*64)      // 80,777,216
#define O_COFS   (O_CCNT  + (size_t)NCELLS*4)
#define O_CURS   (O_COFS  + (size_t)NCELLS*4)
#define O_HIST   (O_CURS  + (size_t)NCELLS*4)       // 256*512*4 = 512 KB (region 1 MB)
#define O_BSUM   (O_HIST  + (size_t)NCELLS*4)
#define O_VCNT   (O_BSUM  + 4096)
#define O_ENTRY  (O_VCNT  + 8192)
#define WS_NEED  (O_ENTRY + (size_t)4*N_PRIM*4)     // ~101 MB

__device__ __forceinline__ int swz(int q) { return q ^ ((q >> 3) & 7); }

// ---------------------------------------------------------------------------
__global__ __launch_bounds__(256) void k_prep(
    const float* __restrict__ centers, const float* __restrict__ scales,
    const float* __restrict__ rotations, const float* __restrict__ colors,
    const float* __restrict__ opac, const float* __restrict__ mvp,
    uint64_t* __restrict__ sortA, float4* __restrict__ rec,
    uint32_t* __restrict__ cellcnt, uint32_t* __restrict__ vcnt)
{
  __shared__ float4 srec[2048];          // 512 prims * 4 float4 (swizzled)
  __shared__ uint32_t swcnt[4];
  int t = threadIdx.x;
  int pair = blockIdx.x*256 + t;
  int p0 = pair*2;
  bool live = p0 < N_PRIM;               // pairs never straddle N (N even)

  float m0=mvp[0], m1=mvp[1], m2=mvp[2],  m3=mvp[3];
  float m4=mvp[4], m5=mvp[5], m6=mvp[6],  m7=mvp[7];
  float m8=mvp[8], m9=mvp[9], m10=mvp[10],m11=mvp[11];

  bool valid0=false, valid1=false;
  uint64_t pk0 = ~0ULL, pk1 = ~0ULL;     // padding sorts strictly last

  if (live) {
    const float2* cp = (const float2*)(centers + (size_t)pair*6);
    float2 ca = cp[0], cb = cp[1], cc = cp[2];
    const float2* sp = (const float2*)(scales + (size_t)pair*6);
    float2 sa = sp[0], sb2 = sp[1], sc2 = sp[2];
    const float4* rp = (const float4*)rotations;
    float4 q0 = rp[p0], q1 = rp[p0+1];
    const float2* colp = (const float2*)(colors + (size_t)pair*6);
    float2 ka = colp[0], kb = colp[1], kc = colp[2];
    float2 o2 = ((const float2*)opac)[pair];

    auto doPrim = [&](int i, float c0, float c1, float c2,
                      float s0, float s1, float s2,
                      float qw, float qx, float qy, float qz,
                      float col0, float col1, float col2, float op,
                      uint64_t& pk, bool& validf, int lidx) {
      float n0 = fmaf(m2,  c2, fmaf(m1, c1, m0*c0)) + m3;
      float n1 = fmaf(m6,  c2, fmaf(m5, c1, m4*c0)) + m7;
      float n2 = fmaf(m10, c2, fmaf(m9, c1, m8*c0)) + m11;
      bool valid = n2 > 0.0f;
      validf = valid;
      float cx = (n0 + 1.0f)*0.5f;
      float cy = (n1 + 1.0f)*0.5f;
      // sort key: exact float bits of clip(z,1e-6) (monotone for positives);
      // invalid -> bits of 1e30f. Stability via idx in low 20 bits.
      uint32_t key32 = valid ? __float_as_uint(fmaxf(n2, 1e-6f)) : 0x7149F2CAu;
      pk = ((uint64_t)key32 << 20) | (uint32_t)i;

      float nrm = sqrtf(qw*qw + qx*qx + qy*qy + qz*qz);
      nrm = fmaxf(nrm, 1e-12f);
      qw /= nrm; qx /= nrm; qy /= nrm; qz /= nrm;
      float R00 = 1.0f - 2.0f*(qy*qy + qz*qz);
      float R01 = 2.0f*(qx*qy - qz*qw);
      float R02 = 2.0f*(qx*qz + qy*qw);
      float R10 = 2.0f*(qx*qy + qz*qw);
      float R11 = 1.0f - 2.0f*(qx*qx + qz*qz);
      float R12 = 2.0f*(qy*qz - qx*qw);
      float R20 = 2.0f*(qx*qz - qy*qw);
      float R21 = 2.0f*(qy*qz + qx*qw);
      float R22 = 1.0f - 2.0f*(qx*qx + qy*qy);
      s0 = fmaxf(s0, 1e-9f); s1 = fmaxf(s1, 1e-9f); s2 = fmaxf(s2, 1e-9f);
      float L00=R00*s0, L01=R01*s1, L02=R02*s2;
      float L10=R10*s0, L11=R11*s1, L12=R12*s2;
      float L20=R20*s0, L21=R21*s1, L22=R22*s2;
      float cv00 = fmaf(L02,L02, fmaf(L01,L01, L00*L00));
      float cv01 = fmaf(L02,L12, fmaf(L01,L11, L00*L10));
      float cv02 = fmaf(L02,L22, fmaf(L01,L21, L00*L20));
      float cv11 = fmaf(L12,L12, fmaf(L11,L11, L10*L10));
      float cv12 = fmaf(L12,L22, fmaf(L11,L21, L10*L20));
      float cv22 = fmaf(L22,L22, fmaf(L21,L21, L20*L20));
      float T00 = fmaf(m2,cv02, fmaf(m1,cv01, m0*cv00));
      float T01 = fmaf(m2,cv12, fmaf(m1,cv11, m0*cv01));
      float T02 = fmaf(m2,cv22, fmaf(m1,cv12, m0*cv02));
      float T10 = fmaf(m6,cv02, fmaf(m5,cv01, m4*cv00));
      float T11 = fmaf(m6,cv12, fmaf(m5,cv11, m4*cv01));
      float T12 = fmaf(m6,cv22, fmaf(m5,cv12, m4*cv02));
      float cc00 = fmaf(T02,m2, fmaf(T01,m1, T00*m0));
      float cc01 = fmaf(T02,m6, fmaf(T01,m5, T00*m4));
      float cc11 = fmaf(T12,m6, fmaf(T11,m5, T10*m4));
      float zc  = fmaxf(n2, 1e-6f);
      float scv = FOCAL_C / zc;
      float sc22 = scv*scv;
      float c00 = cc00*sc22, c01 = cc01*sc22, c11 = cc11*sc22;

      float rx = (3.0f * sqrtf(fmaxf(c00, 0.0f))) / 512.0f;
      float ry = (3.0f * sqrtf(fmaxf(c11, 0.0f))) / 512.0f;
      int x0 = (int)floorf((cx - rx) * 512.0f);
      int x1 = (int)floorf((cx + rx) * 512.0f);
      int y0 = (int)floorf((cy - ry) * 512.0f);
      int y1 = (int)floorf((cy + ry) * 512.0f);
      int cl[4];
      #pragma unroll
      for (int ky = 0; ky < 2; ++ky) {
        int yy = y0 + ky;
        bool vy = (yy <= y1) && (yy >= 0) && (yy < GRID_G);
        #pragma unroll
        for (int kx = 0; kx < 2; ++kx) {
          int xx = x0 + kx;
          bool vx = (xx <= x1) && (xx >= 0) && (xx < GRID_G);
          int cell = (valid && vy && vx) ? (yy*GRID_G + xx) : -1;
          cl[ky*2+kx] = cell;
          if (cell >= 0) atomicAdd(&cellcnt[cell], 1u);
        }
      }
      float opv = fminf(fmaxf(op, 0.0f), 1.0f);
      float vf = valid ? 1.0f : 0.0f;
      int lb = lidx*4;
      srec[swz(lb+0)] = make_float4(cx, cy, c00, c01);
      srec[swz(lb+1)] = make_float4(c11, col0, col1, col2);
      srec[swz(lb+2)] = make_float4(opv, vf, 0.0f, 0.0f);
      srec[swz(lb+3)] = make_float4(__int_as_float(cl[0]), __int_as_float(cl[1]),
                                    __int_as_float(cl[2]), __int_as_float(cl[3]));
    };

    doPrim(p0,   ca.x, ca.y, cb.x, sa.x, sa.y, sb2.x,
           q0.x, q0.y, q0.z, q0.w, ka.x, ka.y, kb.x, o2.x, pk0, valid0, 2*t);
    doPrim(p0+1, cb.y, cc.x, cc.y, sb2.y, sc2.x, sc2.y,
           q1.x, q1.y, q1.z, q1.w, kb.y, kc.x, kc.y, o2.y, pk1, valid1, 2*t+1);
  }

  ((ulonglong2*)sortA)[pair] = make_ulonglong2(pk0, pk1);

  unsigned long long b0 = __ballot(live && valid0);
  unsigned long long b1 = __ballot(live && valid1);
  if ((t & 63) == 0) swcnt[t >> 6] = (uint32_t)(__popcll(b0) + __popcll(b1));
  __syncthreads();
  if (t == 0) vcnt[blockIdx.x] = swcnt[0]+swcnt[1]+swcnt[2]+swcnt[3];

  // coalesced rec writeout
  size_t gbase = (size_t)blockIdx.x*2048;
  for (int q = t; q < 2048; q += 256) {
    size_t gi = gbase + q;
    if (gi < (size_t)N_PRIM*4) rec[gi] = srec[swz(q)];
  }
}

// ---------------- scans --------------------------------------------------
// per-256-chunk exclusive prefix (in place capable) + per-block sums
__global__ void k_scanA(const uint32_t* __restrict__ cnt, uint32_t* __restrict__ ofs,
                        uint32_t* __restrict__ bsum)
{
  __shared__ uint32_t s[256];
  int t = threadIdx.x;
  int i = blockIdx.x*256 + t;
  uint32_t v = cnt[i];
  s[t] = v; __syncthreads();
  for (int o = 1; o < 256; o <<= 1) {
    uint32_t u = (t >= o) ? s[t-o] : 0u; __syncthreads();
    s[t] += u; __syncthreads();
  }
  ofs[i] = s[t] - v;
  if (t == 255) bsum[blockIdx.x] = s[t];
}

// fused: partial = sum(bsum[0..blockIdx)) via block reduce, then add to ofs
// (optionally mirror into cursor). Replaces the 1-block scanB + scanC kernels.
__global__ void k_scanBC(uint32_t* __restrict__ ofs, const uint32_t* __restrict__ bsum,
                         uint32_t* __restrict__ cursor)
{
  __shared__ uint32_t s[256];
  int t = threadIdx.x;
  int bid = blockIdx.x;
  uint32_t acc = 0;
  for (int i = t; i < bid; i += 256) acc += bsum[i];
  s[t] = acc; __syncthreads();
  #pragma unroll
  for (int o = 128; o > 0; o >>= 1) { if (t < o) s[t] += s[t+o]; __syncthreads(); }
  uint32_t partial = s[0];
  int i = bid*256 + t;
  uint32_t v = ofs[i] + partial;
  ofs[i] = v;
  if (cursor) cursor[i] = v;
}

// ---------------- radix sort (4 passes of 8 bits over bits 20..51) ----------
__global__ __launch_bounds__(256) void k_hist(const uint64_t* __restrict__ keys,
                                              uint32_t* __restrict__ hist, int shift)
{
  __shared__ uint32_t h[256];
  int t = threadIdx.x;
  h[t] = 0; __syncthreads();
  const ulonglong2* k2 = (const ulonglong2*)(keys + (size_t)blockIdx.x*EPB);
  #pragma unroll
  for (int j = 0; j < 4; ++j) {
    ulonglong2 w = k2[j*256 + t];
    atomicAdd(&h[(uint32_t)(w.x >> shift) & 255u], 1u);
    atomicAdd(&h[(uint32_t)(w.y >> shift) & 255u], 1u);
  }
  __syncthreads();
  hist[(size_t)t*SB + blockIdx.x] = h[t];
}

__global__ __launch_bounds__(256) void k_scatter(
    const uint64_t* __restrict__ in, uint64_t* __restrict__ outp,
    const uint32_t* __restrict__ hist, int shift)
{
  __shared__ uint32_t s_base[256];
  __shared__ uint32_t lbase[256];
  __shared__ uint32_t s_run[256];
  __shared__ uint32_t s_wcnt[1024];   // [bin][wave]
  __shared__ uint64_t stage[EPB];     // 16 KB
  int t = threadIdx.x;
  int wid = t >> 6, lane = t & 63;
  s_base[t] = hist[(size_t)t*SB + blockIdx.x];
  s_run[t] = 0;
  lbase[t] = 0;
  size_t base = (size_t)blockIdx.x*EPB;
  uint64_t v[8]; uint32_t d[8];
  #pragma unroll
  for (int j = 0; j < 8; ++j) {
    v[j] = in[base + j*256 + t];
    d[j] = (uint32_t)(v[j] >> shift) & 255u;
  }
  __syncthreads();
  #pragma unroll
  for (int j = 0; j < 8; ++j) atomicAdd(&lbase[d[j]], 1u);
  __syncthreads();
  uint32_t mycnt = lbase[t];
  for (int o = 1; o < 256; o <<= 1) {
    uint32_t u = (t >= o) ? lbase[t-o] : 0u; __syncthreads();
    lbase[t] += u; __syncthreads();
  }
  uint32_t myexcl = lbase[t] - mycnt;
  __syncthreads();
  lbase[t] = myexcl;
  __syncthreads();

  #pragma unroll
  for (int j = 0; j < 8; ++j) {           // UNROLLED: keep v[]/d[] in VGPRs
    #pragma unroll
    for (int q0 = 0; q0 < 4; ++q0) s_wcnt[q0*256 + t] = 0;
    __syncthreads();
    unsigned long long m = ~0ULL;
    #pragma unroll
    for (int bit = 0; bit < 8; ++bit) {
      unsigned long long vote = __ballot((d[j] >> bit) & 1);
      m &= ((d[j] >> bit) & 1) ? vote : ~vote;
    }
    uint32_t lr = __popcll(m & ((1ULL << lane) - 1ULL));
    if (lr == 0) s_wcnt[d[j]*4 + wid] = (uint32_t)__popcll(m);
    __syncthreads();
    uint32_t wb = 0;
    #pragma unroll
    for (int w = 0; w < 3; ++w) if (w < wid) wb += s_wcnt[d[j]*4 + w];
    stage[lbase[d[j]] + s_run[d[j]] + wb + lr] = v[j];
    __syncthreads();
    s_run[t] += s_wcnt[t*4] + s_wcnt[t*4+1] + s_wcnt[t*4+2] + s_wcnt[t*4+3];
    __syncthreads();
  }
  // block-sorted stage -> coalesced global writes (runs avg 8 elems = 64B)
  #pragma unroll
  for (int j = 0; j < 8; ++j) {
    int q = j*256 + t;
    uint64_t sv = stage[q];
    uint32_t sd = (uint32_t)(sv >> shift) & 255u;
    outp[s_base[sd] + ((uint32_t)q - lbase[sd])] = sv;
  }
}

// ---------------- result rows (sorted order) + entry emit -------------------
__global__ __launch_bounds__(256) void k_result(
    const uint64_t* __restrict__ sorted, const float4* __restrict__ rec,
    uint32_t* __restrict__ cursor, uint32_t* __restrict__ entry,
    float* __restrict__ out)
{
  __shared__ float rows[64*21];
  int t = threadIdx.x;
  int i = blockIdx.x*256 + t;
  bool liveP = i < N_PRIM;
  float4 a = make_float4(0,0,0,0), b = a, c = a;
  int4 cl = make_int4(-1,-1,-1,-1);
  if (liveP) {
    uint64_t v = sorted[i];
    int o = (int)(v & 0xFFFFFu);
    a = rec[(size_t)o*4]; b = rec[(size_t)o*4+1];
    c = rec[(size_t)o*4+2];
    float4 dd = rec[(size_t)o*4+3];
    cl.x = __float_as_int(dd.x); cl.y = __float_as_int(dd.y);
    cl.z = __float_as_int(dd.z); cl.w = __float_as_int(dd.w);
  }
  float vf = c.y;
  int mychunk = t >> 6;
  int r64 = t & 63;
  int blockRows = min(256, N_PRIM - blockIdx.x*256);
  for (int ch = 0; ch < 4; ++ch) {
    if (mychunk == ch && liveP) {
      float* r = &rows[r64*21];
      r[0]  = 5.0f*vf;
      r[1]  = a.x*vf; r[2] = a.y*vf; r[3] = a.z*vf; r[4] = a.w*vf; r[5] = b.x*vf;
      r[6]  = 0.0f; r[7] = 0.0f; r[8] = 0.0f;
      r[9]  = b.y*vf; r[10] = b.z*vf; r[11] = b.w*vf;
      r[12] = c.x*vf;
      r[13]=0.0f; r[14]=0.0f; r[15]=0.0f; r[16]=0.0f; r[17]=0.0f; r[18]=0.0f; r[19]=0.0f;
    }
    __syncthreads();
    int nrows = min(64, blockRows - ch*64);
    if (nrows > 0) {
      int total = nrows*20;
      float* gout = out + 6 + (size_t)blockIdx.x*5120 + ch*1280;
      for (int g = t; g < total; g += 256) {
        int rr = g/20, cc2 = g - rr*20;
        gout[g] = rows[rr*21+cc2];
      }
    }
    __syncthreads();
  }
  if (liveP) {
    int cc[4] = {cl.x, cl.y, cl.z, cl.w};
    #pragma unroll
    for (int k = 0; k < 4; ++k) {
      if (cc[k] >= 0) {
        uint32_t p = atomicAdd(&cursor[cc[k]], 1u);
        entry[p] = (uint32_t)i;
      }
    }
  }
}

// ---------------- per-cell finalize: sort entries, write grid ---------------
__global__ __launch_bounds__(256) void k_grid(
    const uint32_t* __restrict__ cellcnt, const uint32_t* __restrict__ cellofs,
    const uint32_t* __restrict__ entry, float* __restrict__ out)
{
  int wid = threadIdx.x >> 6;
  int lane = threadIdx.x & 63;
  int cell = blockIdx.x*4 + wid;
  uint32_t cnt = cellcnt[cell];
  uint32_t ofs = cellofs[cell];
  float* g = out + 6 + (size_t)N_PRIM*20 + (size_t)cell*65;
  if (cnt <= 64u) {
    int v = (lane < (int)cnt) ? (int)entry[ofs + lane] : 0x7FFFFFFF;
    #pragma unroll
    for (int k = 2; k <= 64; k <<= 1) {
      #pragma unroll
      for (int j = k>>1; j > 0; j >>= 1) {
        int p = __shfl_xor(v, j, 64);
        bool up = ((lane & k) == 0);
        bool lower = ((lane & j) == 0);
        int mn = min(v,p), mx = max(v,p);
        v = (up == lower) ? mn : mx;
      }
    }
    g[1+lane] = (lane < (int)cnt) ? (float)v : 0.0f;
    if (lane == 0) g[0] = (float)cnt;
  } else {
    int last = -1;
    for (int s = 0; s < 64; ++s) {
      int best = 0x7FFFFFFF;
      for (uint32_t c = lane; c < cnt; c += 64) {
        int v = (int)entry[ofs + c];
        if (v > last && v < best) best = v;
      }
      #pragma unroll
      for (int o = 32; o > 0; o >>= 1) best = min(best, __shfl_xor(best, o, 64));
      if (lane == 0) g[1+s] = (float)best;
      last = best;
    }
    if (lane == 0) g[0] = 64.0f;
  }
}

// ---------------- header ----------------------------------------------------
__global__ void k_header(const uint32_t* __restrict__ vcnt,
                         const float* __restrict__ bg, float* __restrict__ out)
{
  __shared__ uint32_t s[256];
  int t = threadIdx.x;
  uint32_t acc = 0;
  for (int i = t; i < PREP_BLOCKS; i += 256) acc += vcnt[i];
  s[t] = acc; __syncthreads();
  for (int o = 128; o > 0; o >>= 1) { if (t < o) s[t] += s[t+o]; __syncthreads(); }
  if (t == 0) {
    out[0] = (float)s[0];
    out[1] = 512.0f;
    out[2] = 64.0f;
    out[3] = bg[0]; out[4] = bg[1]; out[5] = bg[2];
  }
}

// ---------------------------------------------------------------------------
extern "C" void kernel_launch(void* const* d_in, const int* in_sizes, int n_in,
                              void* d_out, int out_size, void* d_ws, size_t ws_size,
                              hipStream_t stream)
{
  const float* centers   = (const float*)d_in[0];
  const float* scales    = (const float*)d_in[1];
  const float* rotations = (const float*)d_in[2];
  const float* colors    = (const float*)d_in[3];
  const float* opacities = (const float*)d_in[4];
  const float* mvp       = (const float*)d_in[5];
  const float* background= (const float*)d_in[6];
  float* out = (float*)d_out;
  char* ws = (char*)d_ws;
  if (ws_size < WS_NEED) return;

  uint64_t* sortA  = (uint64_t*)(ws + O_SORTA);
  uint64_t* sortB  = (uint64_t*)(ws + O_SORTB);
  float4*   rec    = (float4*)  (ws + O_REC);
  uint32_t* ccnt   = (uint32_t*)(ws + O_CCNT);
  uint32_t* cofs   = (uint32_t*)(ws + O_COFS);
  uint32_t* curs   = (uint32_t*)(ws + O_CURS);
  uint32_t* hist   = (uint32_t*)(ws + O_HIST);
  uint32_t* bsum   = (uint32_t*)(ws + O_BSUM);
  uint32_t* vcnt   = (uint32_t*)(ws + O_VCNT);
  uint32_t* entry  = (uint32_t*)(ws + O_ENTRY);

  hipMemsetAsync(ws + O_CCNT, 0, (size_t)NCELLS*4, stream);

  k_prep<<<PREP_BLOCKS, 256, 0, stream>>>(centers, scales, rotations, colors,
                                          opacities, mvp, sortA, rec, ccnt, vcnt);

  // cell-count scan -> offsets + cursors (262144 = 1024 blocks, 2 dispatches)
  k_scanA <<<NCELLS/256, 256, 0, stream>>>(ccnt, cofs, bsum);
  k_scanBC<<<NCELLS/256, 256, 0, stream>>>(cofs, bsum, curs);

  // 4-pass radix on bits 20..51 of packed (key32<<20 | idx)
  uint64_t *kin = sortA, *kout = sortB;
  const int shifts[4] = {20, 28, 36, 44};
  for (int pass = 0; pass < 4; ++pass) {
    k_hist<<<SB, 256, 0, stream>>>(kin, hist, shifts[pass]);
    // scan hist: 256*SB = 131072 entries = 512 blocks, 2 dispatches
    k_scanA <<<(256*SB)/256, 256, 0, stream>>>(hist, hist, bsum);
    k_scanBC<<<(256*SB)/256, 256, 0, stream>>>(hist, bsum, (uint32_t*)nullptr);
    k_scatter<<<SB, 256, 0, stream>>>(kin, kout, hist, shifts[pass]);
    uint64_t* tmp = kin; kin = kout; kout = tmp;
  }
  // 4 passes: sorted array back in sortA (== kin)

  k_result<<<(N_PRIM+255)/256, 256, 0, stream>>>(kin, rec, curs, entry, out);
  k_grid  <<<NCELLS/4, 256, 0, stream>>>(ccnt, cofs, entry, out);
  k_header<<<1, 256, 0, stream>>>(vcnt, background, out);
}

// Round 6
// 423.265 us; speedup vs baseline: 2.3066x; 1.0076x over previous
//
#include <hip/hip_runtime.h>
#include <stdint.h>

#pragma clang fp contract(off)

#define N_PRIM   1000000
#define GRID_G   512
#define NCELLS   (GRID_G*GRID_G)          // 262144
#define FOCAL_C  768.0f
#define NP2      1048576                  // 2^20 padded count
#define SB       1024                     // sort blocks
#define EPB      1024                     // elems per sort block (256 thr * 4)
#define PREP_BLOCKS 2048                  // 512 prims per block

// ---------------- workspace layout (bytes) ----------------
#define O_SORTA  ((size_t)0)
#define O_SORTB  (O_SORTA + (size_t)NP2*8)          // 8,388,608
#define O_REC    (O_SORTB + (size_t)NP2*8)          // 16,777,216
#define O_CCNT   (O_REC   + (size_t)N_PRIM*64)      // 80,777,216
#define O_COFS   (O_CCNT  + (size_t)NCELLS*4)
#define O_CURS   (O_COFS  + (size_t)NCELLS*4)
#define O_HIST   (O_CURS  + (size_t)NCELLS*4)       // 256*1024*4 = 1 MB
#define O_BSUM   (O_HIST  + (size_t)NCELLS*4)
#define O_VCNT   (O_BSUM  + 8192)
#define O_ENTRY  (O_VCNT  + 8192)
#define WS_NEED  (O_ENTRY + (size_t)4*N_PRIM*4)     // ~101 MB

__device__ __forceinline__ int swz(int q) { return q ^ ((q >> 3) & 7); }

// ---------------------------------------------------------------------------
__global__ __launch_bounds__(256) void k_prep(
    const float* __restrict__ centers, const float* __restrict__ scales,
    const float* __restrict__ rotations, const float* __restrict__ colors,
    const float* __restrict__ opac, const float* __restrict__ mvp,
    uint64_t* __restrict__ sortA, float4* __restrict__ rec,
    uint32_t* __restrict__ cellcnt, uint32_t* __restrict__ vcnt)
{
  __shared__ float4 srec[2048];          // 512 prims * 4 float4 (swizzled)
  __shared__ uint32_t swcnt[4];
  int t = threadIdx.x;
  int pair = blockIdx.x*256 + t;
  int p0 = pair*2;
  bool live = p0 < N_PRIM;               // pairs never straddle N (N even)

  float m0=mvp[0], m1=mvp[1], m2=mvp[2],  m3=mvp[3];
  float m4=mvp[4], m5=mvp[5], m6=mvp[6],  m7=mvp[7];
  float m8=mvp[8], m9=mvp[9], m10=mvp[10],m11=mvp[11];

  bool valid0=false, valid1=false;
  uint64_t pk0 = ~0ULL, pk1 = ~0ULL;     // padding sorts strictly last

  if (live) {
    const float2* cp = (const float2*)(centers + (size_t)pair*6);
    float2 ca = cp[0], cb = cp[1], cc = cp[2];
    const float2* sp = (const float2*)(scales + (size_t)pair*6);
    float2 sa = sp[0], sb2 = sp[1], sc2 = sp[2];
    const float4* rp = (const float4*)rotations;
    float4 q0 = rp[p0], q1 = rp[p0+1];
    const float2* colp = (const float2*)(colors + (size_t)pair*6);
    float2 ka = colp[0], kb = colp[1], kc = colp[2];
    float2 o2 = ((const float2*)opac)[pair];

    auto doPrim = [&](int i, float c0, float c1, float c2,
                      float s0, float s1, float s2,
                      float qw, float qx, float qy, float qz,
                      float col0, float col1, float col2, float op,
                      uint64_t& pk, bool& validf, int lidx) {
      float n0 = fmaf(m2,  c2, fmaf(m1, c1, m0*c0)) + m3;
      float n1 = fmaf(m6,  c2, fmaf(m5, c1, m4*c0)) + m7;
      float n2 = fmaf(m10, c2, fmaf(m9, c1, m8*c0)) + m11;
      bool valid = n2 > 0.0f;
      validf = valid;
      float cx = (n0 + 1.0f)*0.5f;
      float cy = (n1 + 1.0f)*0.5f;
      // sort key: exact float bits of clip(z,1e-6) (monotone for positives);
      // invalid -> bits of 1e30f. Stability via idx in low 20 bits.
      uint32_t key32 = valid ? __float_as_uint(fmaxf(n2, 1e-6f)) : 0x7149F2CAu;
      pk = ((uint64_t)key32 << 20) | (uint32_t)i;

      float nrm = sqrtf(qw*qw + qx*qx + qy*qy + qz*qz);
      nrm = fmaxf(nrm, 1e-12f);
      qw /= nrm; qx /= nrm; qy /= nrm; qz /= nrm;
      float R00 = 1.0f - 2.0f*(qy*qy + qz*qz);
      float R01 = 2.0f*(qx*qy - qz*qw);
      float R02 = 2.0f*(qx*qz + qy*qw);
      float R10 = 2.0f*(qx*qy + qz*qw);
      float R11 = 1.0f - 2.0f*(qx*qx + qz*qz);
      float R12 = 2.0f*(qy*qz - qx*qw);
      float R20 = 2.0f*(qx*qz - qy*qw);
      float R21 = 2.0f*(qy*qz + qx*qw);
      float R22 = 1.0f - 2.0f*(qx*qx + qy*qy);
      s0 = fmaxf(s0, 1e-9f); s1 = fmaxf(s1, 1e-9f); s2 = fmaxf(s2, 1e-9f);
      float L00=R00*s0, L01=R01*s1, L02=R02*s2;
      float L10=R10*s0, L11=R11*s1, L12=R12*s2;
      float L20=R20*s0, L21=R21*s1, L22=R22*s2;
      float cv00 = fmaf(L02,L02, fmaf(L01,L01, L00*L00));
      float cv01 = fmaf(L02,L12, fmaf(L01,L11, L00*L10));
      float cv02 = fmaf(L02,L22, fmaf(L01,L21, L00*L20));
      float cv11 = fmaf(L12,L12, fmaf(L11,L11, L10*L10));
      float cv12 = fmaf(L12,L22, fmaf(L11,L21, L10*L20));
      float cv22 = fmaf(L22,L22, fmaf(L21,L21, L20*L20));
      float T00 = fmaf(m2,cv02, fmaf(m1,cv01, m0*cv00));
      float T01 = fmaf(m2,cv12, fmaf(m1,cv11, m0*cv01));
      float T02 = fmaf(m2,cv22, fmaf(m1,cv12, m0*cv02));
      float T10 = fmaf(m6,cv02, fmaf(m5,cv01, m4*cv00));
      float T11 = fmaf(m6,cv12, fmaf(m5,cv11, m4*cv01));
      float T12 = fmaf(m6,cv22, fmaf(m5,cv12, m4*cv02));
      float cc00 = fmaf(T02,m2, fmaf(T01,m1, T00*m0));
      float cc01 = fmaf(T02,m6, fmaf(T01,m5, T00*m4));
      float cc11 = fmaf(T12,m6, fmaf(T11,m5, T10*m4));
      float zc  = fmaxf(n2, 1e-6f);
      float scv = FOCAL_C / zc;
      float sc22 = scv*scv;
      float c00 = cc00*sc22, c01 = cc01*sc22, c11 = cc11*sc22;

      float rx = (3.0f * sqrtf(fmaxf(c00, 0.0f))) / 512.0f;
      float ry = (3.0f * sqrtf(fmaxf(c11, 0.0f))) / 512.0f;
      int x0 = (int)floorf((cx - rx) * 512.0f);
      int x1 = (int)floorf((cx + rx) * 512.0f);
      int y0 = (int)floorf((cy - ry) * 512.0f);
      int y1 = (int)floorf((cy + ry) * 512.0f);
      int cl[4];
      #pragma unroll
      for (int ky = 0; ky < 2; ++ky) {
        int yy = y0 + ky;
        bool vy = (yy <= y1) && (yy >= 0) && (yy < GRID_G);
        #pragma unroll
        for (int kx = 0; kx < 2; ++kx) {
          int xx = x0 + kx;
          bool vx = (xx <= x1) && (xx >= 0) && (xx < GRID_G);
          int cell = (valid && vy && vx) ? (yy*GRID_G + xx) : -1;
          cl[ky*2+kx] = cell;
          if (cell >= 0) atomicAdd(&cellcnt[cell], 1u);
        }
      }
      float opv = fminf(fmaxf(op, 0.0f), 1.0f);
      float vf = valid ? 1.0f : 0.0f;
      int lb = lidx*4;
      srec[swz(lb+0)] = make_float4(cx, cy, c00, c01);
      srec[swz(lb+1)] = make_float4(c11, col0, col1, col2);
      srec[swz(lb+2)] = make_float4(opv, vf, 0.0f, 0.0f);
      srec[swz(lb+3)] = make_float4(__int_as_float(cl[0]), __int_as_float(cl[1]),
                                    __int_as_float(cl[2]), __int_as_float(cl[3]));
    };

    doPrim(p0,   ca.x, ca.y, cb.x, sa.x, sa.y, sb2.x,
           q0.x, q0.y, q0.z, q0.w, ka.x, ka.y, kb.x, o2.x, pk0, valid0, 2*t);
    doPrim(p0+1, cb.y, cc.x, cc.y, sb2.y, sc2.x, sc2.y,
           q1.x, q1.y, q1.z, q1.w, kb.y, kc.x, kc.y, o2.y, pk1, valid1, 2*t+1);
  }

  ((ulonglong2*)sortA)[pair] = make_ulonglong2(pk0, pk1);

  unsigned long long b0 = __ballot(live && valid0);
  unsigned long long b1 = __ballot(live && valid1);
  if ((t & 63) == 0) swcnt[t >> 6] = (uint32_t)(__popcll(b0) + __popcll(b1));
  __syncthreads();
  if (t == 0) vcnt[blockIdx.x] = swcnt[0]+swcnt[1]+swcnt[2]+swcnt[3];

  // coalesced rec writeout
  size_t gbase = (size_t)blockIdx.x*2048;
  for (int q = t; q < 2048; q += 256) {
    size_t gi = gbase + q;
    if (gi < (size_t)N_PRIM*4) rec[gi] = srec[swz(q)];
  }
}

// ---------------- scans --------------------------------------------------
// per-256-chunk exclusive prefix + per-block sums
__global__ void k_scanA(const uint32_t* __restrict__ cnt, uint32_t* __restrict__ ofs,
                        uint32_t* __restrict__ bsum)
{
  __shared__ uint32_t s[256];
  int t = threadIdx.x;
  int i = blockIdx.x*256 + t;
  uint32_t v = cnt[i];
  s[t] = v; __syncthreads();
  for (int o = 1; o < 256; o <<= 1) {
    uint32_t u = (t >= o) ? s[t-o] : 0u; __syncthreads();
    s[t] += u; __syncthreads();
  }
  ofs[i] = s[t] - v;
  if (t == 255) bsum[blockIdx.x] = s[t];
}

// fused: partial = sum(bsum[0..blockIdx)), add to ofs (optionally mirror into
// cursor). Block 0 optionally also writes the output header (vcnt reduce + bg).
__global__ void k_scanBC(uint32_t* __restrict__ ofs, const uint32_t* __restrict__ bsum,
                         uint32_t* __restrict__ cursor,
                         const uint32_t* __restrict__ vcnt,
                         const float* __restrict__ bg, float* __restrict__ out)
{
  __shared__ uint32_t s[256];
  int t = threadIdx.x;
  int bid = blockIdx.x;
  uint32_t acc = 0;
  for (int i = t; i < bid; i += 256) acc += bsum[i];
  s[t] = acc; __syncthreads();
  #pragma unroll
  for (int o = 128; o > 0; o >>= 1) { if (t < o) s[t] += s[t+o]; __syncthreads(); }
  uint32_t partial = s[0];
  int i = bid*256 + t;
  uint32_t v = ofs[i] + partial;
  ofs[i] = v;
  if (cursor) cursor[i] = v;

  if (vcnt && bid == 0) {   // header fold-in (one extra reduce on block 0)
    __syncthreads();
    uint32_t a2 = 0;
    for (int i2 = t; i2 < PREP_BLOCKS; i2 += 256) a2 += vcnt[i2];
    s[t] = a2; __syncthreads();
    #pragma unroll
    for (int o = 128; o > 0; o >>= 1) { if (t < o) s[t] += s[t+o]; __syncthreads(); }
    if (t == 0) {
      out[0] = (float)s[0];
      out[1] = 512.0f;
      out[2] = 64.0f;
      out[3] = bg[0]; out[4] = bg[1]; out[5] = bg[2];
    }
  }
}

// ---------------- radix sort (4 passes of 8 bits over bits 20..51) ----------
__global__ __launch_bounds__(256) void k_hist(const uint64_t* __restrict__ keys,
                                              uint32_t* __restrict__ hist, int shift)
{
  __shared__ uint32_t h[256];
  int t = threadIdx.x;
  h[t] = 0; __syncthreads();
  const ulonglong2* k2 = (const ulonglong2*)(keys + (size_t)blockIdx.x*EPB);
  #pragma unroll
  for (int j = 0; j < 2; ++j) {
    ulonglong2 w = k2[j*256 + t];
    atomicAdd(&h[(uint32_t)(w.x >> shift) & 255u], 1u);
    atomicAdd(&h[(uint32_t)(w.y >> shift) & 255u], 1u);
  }
  __syncthreads();
  hist[(size_t)t*SB + blockIdx.x] = h[t];
}

__global__ __launch_bounds__(256) void k_scatter(
    const uint64_t* __restrict__ in, uint64_t* __restrict__ outp,
    const uint32_t* __restrict__ hist, int shift)
{
  __shared__ uint32_t s_base[256];
  __shared__ uint32_t lbase[256];
  __shared__ uint32_t s_run[256];
  __shared__ uint32_t s_wcnt[1024];   // [bin][wave]
  __shared__ uint64_t stage[EPB];     // 8 KB
  int t = threadIdx.x;
  int wid = t >> 6, lane = t & 63;
  s_base[t] = hist[(size_t)t*SB + blockIdx.x];
  s_run[t] = 0;
  lbase[t] = 0;
  size_t base = (size_t)blockIdx.x*EPB;
  uint64_t v[4]; uint32_t d[4];
  #pragma unroll
  for (int j = 0; j < 4; ++j) {
    v[j] = in[base + j*256 + t];
    d[j] = (uint32_t)(v[j] >> shift) & 255u;
  }
  __syncthreads();
  #pragma unroll
  for (int j = 0; j < 4; ++j) atomicAdd(&lbase[d[j]], 1u);
  __syncthreads();
  uint32_t mycnt = lbase[t];
  for (int o = 1; o < 256; o <<= 1) {
    uint32_t u = (t >= o) ? lbase[t-o] : 0u; __syncthreads();
    lbase[t] += u; __syncthreads();
  }
  uint32_t myexcl = lbase[t] - mycnt;
  __syncthreads();
  lbase[t] = myexcl;
  __syncthreads();

  #pragma unroll
  for (int j = 0; j < 4; ++j) {           // unrolled: v[]/d[] stay in VGPRs
    #pragma unroll
    for (int q0 = 0; q0 < 4; ++q0) s_wcnt[q0*256 + t] = 0;
    __syncthreads();
    unsigned long long m = ~0ULL;
    #pragma unroll
    for (int bit = 0; bit < 8; ++bit) {
      unsigned long long vote = __ballot((d[j] >> bit) & 1);
      m &= ((d[j] >> bit) & 1) ? vote : ~vote;
    }
    uint32_t lr = __popcll(m & ((1ULL << lane) - 1ULL));
    if (lr == 0) s_wcnt[d[j]*4 + wid] = (uint32_t)__popcll(m);
    __syncthreads();
    uint32_t wb = 0;
    #pragma unroll
    for (int w = 0; w < 3; ++w) if (w < wid) wb += s_wcnt[d[j]*4 + w];
    stage[lbase[d[j]] + s_run[d[j]] + wb + lr] = v[j];
    __syncthreads();
    s_run[t] += s_wcnt[t*4] + s_wcnt[t*4+1] + s_wcnt[t*4+2] + s_wcnt[t*4+3];
    __syncthreads();
  }
  // block-sorted stage -> coalesced global writes
  #pragma unroll
  for (int j = 0; j < 4; ++j) {
    int q = j*256 + t;
    uint64_t sv = stage[q];
    uint32_t sd = (uint32_t)(sv >> shift) & 255u;
    outp[s_base[sd] + ((uint32_t)q - lbase[sd])] = sv;
  }
}

// ---------------- result rows (sorted order) + entry emit -------------------
__global__ __launch_bounds__(256) void k_result(
    const uint64_t* __restrict__ sorted, const float4* __restrict__ rec,
    uint32_t* __restrict__ cursor, uint32_t* __restrict__ entry,
    float* __restrict__ out)
{
  __shared__ float rows[64*21];
  int t = threadIdx.x;
  int i = blockIdx.x*256 + t;
  bool liveP = i < N_PRIM;
  float4 a = make_float4(0,0,0,0), b = a, c = a;
  int4 cl = make_int4(-1,-1,-1,-1);
  if (liveP) {
    uint64_t v = sorted[i];
    int o = (int)(v & 0xFFFFFu);
    a = rec[(size_t)o*4]; b = rec[(size_t)o*4+1];
    c = rec[(size_t)o*4+2];
    float4 dd = rec[(size_t)o*4+3];
    cl.x = __float_as_int(dd.x); cl.y = __float_as_int(dd.y);
    cl.z = __float_as_int(dd.z); cl.w = __float_as_int(dd.w);
  }
  float vf = c.y;
  int mychunk = t >> 6;
  int r64 = t & 63;
  int blockRows = min(256, N_PRIM - blockIdx.x*256);
  for (int ch = 0; ch < 4; ++ch) {
    if (mychunk == ch && liveP) {
      float* r = &rows[r64*21];
      r[0]  = 5.0f*vf;
      r[1]  = a.x*vf; r[2] = a.y*vf; r[3] = a.z*vf; r[4] = a.w*vf; r[5] = b.x*vf;
      r[6]  = 0.0f; r[7] = 0.0f; r[8] = 0.0f;
      r[9]  = b.y*vf; r[10] = b.z*vf; r[11] = b.w*vf;
      r[12] = c.x*vf;
      r[13]=0.0f; r[14]=0.0f; r[15]=0.0f; r[16]=0.0f; r[17]=0.0f; r[18]=0.0f; r[19]=0.0f;
    }
    __syncthreads();
    int nrows = min(64, blockRows - ch*64);
    if (nrows > 0) {
      int total = nrows*20;
      float* gout = out + 6 + (size_t)blockIdx.x*5120 + ch*1280;
      for (int g = t; g < total; g += 256) {
        int rr = g/20, cc2 = g - rr*20;
        gout[g] = rows[rr*21+cc2];
      }
    }
    __syncthreads();
  }
  if (liveP) {
    int cc[4] = {cl.x, cl.y, cl.z, cl.w};
    #pragma unroll
    for (int k = 0; k < 4; ++k) {
      if (cc[k] >= 0) {
        uint32_t p = atomicAdd(&cursor[cc[k]], 1u);
        entry[p] = (uint32_t)i;
      }
    }
  }
}

// ---------------- per-cell finalize: sort entries, write grid ---------------
__global__ __launch_bounds__(256) void k_grid(
    const uint32_t* __restrict__ cellcnt, const uint32_t* __restrict__ cellofs,
    const uint32_t* __restrict__ entry, float* __restrict__ out)
{
  int wid = threadIdx.x >> 6;
  int lane = threadIdx.x & 63;
  int cell = blockIdx.x*4 + wid;
  uint32_t cnt = cellcnt[cell];
  uint32_t ofs = cellofs[cell];
  float* g = out + 6 + (size_t)N_PRIM*20 + (size_t)cell*65;
  if (cnt <= 64u) {
    int v = (lane < (int)cnt) ? (int)entry[ofs + lane] : 0x7FFFFFFF;
    #pragma unroll
    for (int k = 2; k <= 64; k <<= 1) {
      #pragma unroll
      for (int j = k>>1; j > 0; j >>= 1) {
        int p = __shfl_xor(v, j, 64);
        bool up = ((lane & k) == 0);
        bool lower = ((lane & j) == 0);
        int mn = min(v,p), mx = max(v,p);
        v = (up == lower) ? mn : mx;
      }
    }
    g[1+lane] = (lane < (int)cnt) ? (float)v : 0.0f;
    if (lane == 0) g[0] = (float)cnt;
  } else {
    int last = -1;
    for (int s = 0; s < 64; ++s) {
      int best = 0x7FFFFFFF;
      for (uint32_t c = lane; c < cnt; c += 64) {
        int v = (int)entry[ofs + c];
        if (v > last && v < best) best = v;
      }
      #pragma unroll
      for (int o = 32; o > 0; o >>= 1) best = min(best, __shfl_xor(best, o, 64));
      if (lane == 0) g[1+s] = (float)best;
      last = best;
    }
    if (lane == 0) g[0] = 64.0f;
  }
}

// ---------------------------------------------------------------------------
extern "C" void kernel_launch(void* const* d_in, const int* in_sizes, int n_in,
                              void* d_out, int out_size, void* d_ws, size_t ws_size,
                              hipStream_t stream)
{
  const float* centers   = (const float*)d_in[0];
  const float* scales    = (const float*)d_in[1];
  const float* rotations = (const float*)d_in[2];
  const float* colors    = (const float*)d_in[3];
  const float* opacities = (const float*)d_in[4];
  const float* mvp       = (const float*)d_in[5];
  const float* background= (const float*)d_in[6];
  float* out = (float*)d_out;
  char* ws = (char*)d_ws;
  if (ws_size < WS_NEED) return;

  uint64_t* sortA  = (uint64_t*)(ws + O_SORTA);
  uint64_t* sortB  = (uint64_t*)(ws + O_SORTB);
  float4*   rec    = (float4*)  (ws + O_REC);
  uint32_t* ccnt   = (uint32_t*)(ws + O_CCNT);
  uint32_t* cofs   = (uint32_t*)(ws + O_COFS);
  uint32_t* curs   = (uint32_t*)(ws + O_CURS);
  uint32_t* hist   = (uint32_t*)(ws + O_HIST);
  uint32_t* bsum   = (uint32_t*)(ws + O_BSUM);
  uint32_t* vcnt   = (uint32_t*)(ws + O_VCNT);
  uint32_t* entry  = (uint32_t*)(ws + O_ENTRY);

  hipMemsetAsync(ws + O_CCNT, 0, (size_t)NCELLS*4, stream);

  k_prep<<<PREP_BLOCKS, 256, 0, stream>>>(centers, scales, rotations, colors,
                                          opacities, mvp, sortA, rec, ccnt, vcnt);

  // cell-count scan -> offsets + cursors (+ header via block 0)
  k_scanA <<<NCELLS/256, 256, 0, stream>>>(ccnt, cofs, bsum);
  k_scanBC<<<NCELLS/256, 256, 0, stream>>>(cofs, bsum, curs, vcnt, background, out);

  // 4-pass radix on bits 20..51 of packed (key32<<20 | idx)
  uint64_t *kin = sortA, *kout = sortB;
  const int shifts[4] = {20, 28, 36, 44};
  for (int pass = 0; pass < 4; ++pass) {
    k_hist<<<SB, 256, 0, stream>>>(kin, hist, shifts[pass]);
    // scan hist: 256*SB = 262144 entries = 1024 blocks
    k_scanA <<<(256*SB)/256, 256, 0, stream>>>(hist, hist, bsum);
    k_scanBC<<<(256*SB)/256, 256, 0, stream>>>(hist, bsum, (uint32_t*)nullptr,
                                               (const uint32_t*)nullptr,
                                               (const float*)nullptr, (float*)nullptr);
    k_scatter<<<SB, 256, 0, stream>>>(kin, kout, hist, shifts[pass]);
    uint64_t* tmp = kin; kin = kout; kout = tmp;
  }
  // 4 passes: sorted array back in sortA (== kin)

  k_result<<<(N_PRIM+255)/256, 256, 0, stream>>>(kin, rec, curs, entry, out);
  k_grid  <<<NCELLS/4, 256, 0, stream>>>(ccnt, cofs, entry, out);
}